// Round 5
// baseline (818.774 us; speedup 1.0000x reference)
//
#include <hip/hip_runtime.h>
#include <hip/hip_bf16.h>

#define LSEQ 2048
#define BB   2048
#define TT   7
#define REC  52   // 49 matrix + scale + score + maskcnt (float), 208 B = 16B-aligned

// ---------------------------------------------------------------------------
// Kernel 1: 2 threads per (batch, chunk). Thread h in {0,1} builds the
// composite operator for its half-chunk (C/2 steps) in exp-space:
//   M <- M x (E o colscale(exp(em_i)))     (thread-private, 343 fma/step)
// then h=1 publishes its half via LDS and h=0 computes M = MA x MB, renorms,
// and writes the 52-float record. Gold-path score/mask-count are accumulated
// per half and summed at the merge. E = exp(transitions) cached in registers,
// selected by the contagion flag (reloaded only when the flag flips).
// ---------------------------------------------------------------------------
template<int K>
__global__ __launch_bounds__(256, 4)
void crf_chunk_kernel(const float* __restrict__ em,
                      const int*   __restrict__ tags,
                      const int*   __restrict__ qmask,
                      const int*   __restrict__ mask,
                      const float* __restrict__ self_t,
                      const float* __restrict__ other_t,
                      float* __restrict__ recs) {
  constexpr int C  = LSEQ / K;   // steps per chunk
  constexpr int C2 = C / 2;      // steps per thread
  __shared__ __align__(16) float sE[2][52];   // exp(transitions): [0]=self, [1]=other
  __shared__ __align__(16) float sT[2][52];   // raw transitions (gold-path score)
  __shared__ float sMB[128][49];              // second-half matrices
  __shared__ float sAux[128][2];              // sc, mc from h=1

  int tid = threadIdx.x;
  if (tid < 49) {
    float sv = self_t[tid];
    float ov = other_t[tid];
    sE[0][tid] = expf(sv);
    sE[1][tid] = expf(ov);
    sT[0][tid] = sv;
    sT[1][tid] = ov;
  } else if (tid < 52) {
    sE[0][tid] = 0.f; sE[1][tid] = 0.f;
    sT[0][tid] = 0.f; sT[1][tid] = 0.f;
  }
  __syncthreads();

  int h  = tid >> 7;            // half: 0 = first C/2 steps, 1 = second
  int bl = tid & 127;           // chunk slot within block
  int chunkIdx = blockIdx.x * 128 + bl;
  int b = chunkIdx & (BB - 1);
  int c = chunkIdx >> 11;       // chunkIdx / BB

  float M[49];
#pragma unroll
  for (int s = 0; s < 7; ++s)
#pragma unroll
    for (int t = 0; t < 7; ++t) M[s*7+t] = (s == t) ? 1.0f : 0.0f;

  float sc = 0.0f;
  int   mc = 0;
  int i0    = c * C + h * C2;
  int i_end = i0 + C2;
  int tp, qp;
  if (i0 == 0) {                // c==0, h==0: step 0 is the alpha-init
    mc = mask[b];
    tp = tags[b];
    qp = qmask[b];
    i0 = 1;
  } else {
    tp = tags[(size_t)(i0 - 1) * BB + b];
    qp = qmask[(size_t)(i0 - 1) * BB + b];
  }

  const float* em_p = em    + ((size_t)i0 * BB + b) * TT;
  const int*   qm_p = qmask + (size_t)i0 * BB + b;
  const int*   mk_p = mask  + (size_t)i0 * BB + b;
  const int*   tg_p = tags  + (size_t)i0 * BB + b;

  float Er[49];
  int contPrev = -1;            // force initial load

  for (int i = i0; i < i_end; ++i) {
    const float* eb = em_p;
    float e0 = eb[0], e1 = eb[1], e2 = eb[2], e3 = eb[3],
          e4 = eb[4], e5 = eb[5], e6 = eb[6];
    int tg = *tg_p;
    int qm = *qm_p;
    int mi = *mk_p;
    int cont = (qm != qp) ? 1 : 0;

    if (__any(cont != contPrev)) {
      const float4* p = reinterpret_cast<const float4*>(sE[cont]);
#pragma unroll
      for (int k2 = 0; k2 < 12; ++k2) {
        float4 v = p[k2];
        Er[4*k2+0] = v.x; Er[4*k2+1] = v.y; Er[4*k2+2] = v.z; Er[4*k2+3] = v.w;
      }
      Er[48] = sE[cont][48];
      contPrev = cont;
    }

    float ee0 = __expf(e0), ee1 = __expf(e1), ee2 = __expf(e2), ee3 = __expf(e3),
          ee4 = __expf(e4), ee5 = __expf(e5), ee6 = __expf(e6);

    // gold-path score
    float etag = eb[tg];
    float ttag = sT[cont][tp * TT + tg];
    if (mi) { sc += ttag + etag; ++mc; }
    tp = tg; qp = qm;

    if (!__any(mi == 0)) {
#pragma unroll
      for (int s = 0; s < 7; ++s) {
        float t0 = 0.f, t1 = 0.f, t2 = 0.f, t3 = 0.f, t4 = 0.f, t5 = 0.f, t6 = 0.f;
#pragma unroll
        for (int r = 0; r < 7; ++r) {
          float mr = M[s*7+r];
          t0 = fmaf(mr, Er[r*7+0], t0);
          t1 = fmaf(mr, Er[r*7+1], t1);
          t2 = fmaf(mr, Er[r*7+2], t2);
          t3 = fmaf(mr, Er[r*7+3], t3);
          t4 = fmaf(mr, Er[r*7+4], t4);
          t5 = fmaf(mr, Er[r*7+5], t5);
          t6 = fmaf(mr, Er[r*7+6], t6);
        }
        M[s*7+0] = t0 * ee0; M[s*7+1] = t1 * ee1; M[s*7+2] = t2 * ee2;
        M[s*7+3] = t3 * ee3; M[s*7+4] = t4 * ee4; M[s*7+5] = t5 * ee5;
        M[s*7+6] = t6 * ee6;
      }
    } else {
#pragma unroll
      for (int s = 0; s < 7; ++s) {
        float t0 = 0.f, t1 = 0.f, t2 = 0.f, t3 = 0.f, t4 = 0.f, t5 = 0.f, t6 = 0.f;
#pragma unroll
        for (int r = 0; r < 7; ++r) {
          float mr = M[s*7+r];
          t0 = fmaf(mr, Er[r*7+0], t0);
          t1 = fmaf(mr, Er[r*7+1], t1);
          t2 = fmaf(mr, Er[r*7+2], t2);
          t3 = fmaf(mr, Er[r*7+3], t3);
          t4 = fmaf(mr, Er[r*7+4], t4);
          t5 = fmaf(mr, Er[r*7+5], t5);
          t6 = fmaf(mr, Er[r*7+6], t6);
        }
        M[s*7+0] = mi ? t0 * ee0 : M[s*7+0];
        M[s*7+1] = mi ? t1 * ee1 : M[s*7+1];
        M[s*7+2] = mi ? t2 * ee2 : M[s*7+2];
        M[s*7+3] = mi ? t3 * ee3 : M[s*7+3];
        M[s*7+4] = mi ? t4 * ee4 : M[s*7+4];
        M[s*7+5] = mi ? t5 * ee5 : M[s*7+5];
        M[s*7+6] = mi ? t6 * ee6 : M[s*7+6];
      }
    }

    em_p += (size_t)BB * TT;
    qm_p += BB; mk_p += BB; tg_p += BB;
  }

  // ---- merge halves: record = MA x MB ----
  if (h == 1) {
#pragma unroll
    for (int t = 0; t < 49; ++t) sMB[bl][t] = M[t];
    sAux[bl][0] = sc;
    sAux[bl][1] = (float)mc;
  }
  __syncthreads();
  if (h == 0) {
    sc += sAux[bl][0];
    mc += (int)sAux[bl][1];

#pragma unroll
    for (int s = 0; s < 7; ++s) {
      float p0 = 0.f, p1 = 0.f, p2 = 0.f, p3 = 0.f, p4 = 0.f, p5 = 0.f, p6 = 0.f;
#pragma unroll
      for (int r = 0; r < 7; ++r) {
        float mr = M[s*7+r];
        p0 = fmaf(mr, sMB[bl][r*7+0], p0);
        p1 = fmaf(mr, sMB[bl][r*7+1], p1);
        p2 = fmaf(mr, sMB[bl][r*7+2], p2);
        p3 = fmaf(mr, sMB[bl][r*7+3], p3);
        p4 = fmaf(mr, sMB[bl][r*7+4], p4);
        p5 = fmaf(mr, sMB[bl][r*7+5], p5);
        p6 = fmaf(mr, sMB[bl][r*7+6], p6);
      }
      M[s*7+0] = p0; M[s*7+1] = p1; M[s*7+2] = p2; M[s*7+3] = p3;
      M[s*7+4] = p4; M[s*7+5] = p5; M[s*7+6] = p6;
    }

    float mx = M[0];
#pragma unroll
    for (int t = 1; t < 49; ++t) mx = fmaxf(mx, M[t]);
    float inv = 1.0f / mx;

    float outv[52];
#pragma unroll
    for (int t = 0; t < 49; ++t) outv[t] = M[t] * inv;
    outv[49] = logf(mx);
    outv[50] = sc;
    outv[51] = (float)mc;

    float4* rp = reinterpret_cast<float4*>(recs + ((size_t)c * BB + b) * REC);
#pragma unroll
    for (int k2 = 0; k2 < 13; ++k2)
      rp[k2] = make_float4(outv[4*k2+0], outv[4*k2+1], outv[4*k2+2], outv[4*k2+3]);
  }
}

// ---------------------------------------------------------------------------
// Kernel 2: one wave per batch; sequentially fold the K chunk operators into
// the alpha vector (exp-space, renormalized each step), then finish score/logZ.
// ---------------------------------------------------------------------------
__global__ __launch_bounds__(64)
void crf_combine_kernel(const float* __restrict__ recs,
                        const float* __restrict__ em,
                        const int*   __restrict__ tags,
                        const float* __restrict__ start_t,
                        const float* __restrict__ end_t,
                        float* __restrict__ results,
                        int K) {
  int b = blockIdx.x;
  int j = threadIdx.x;
  __shared__ float lds[REC];

  float al[TT];
#pragma unroll
  for (int t = 0; t < TT; ++t) al[t] = expf(start_t[t] + em[(size_t)b * TT + t]);

  float lacc = 0.f, sc = 0.f, mcf = 0.f;
  float r = (j < REC) ? recs[(size_t)b * REC + j] : 0.f;   // record (c=0, b)

  for (int c = 0; c < K; ++c) {
    if (j < REC) lds[j] = r;
    __syncthreads();
    if (c + 1 < K && j < REC)
      r = recs[((size_t)(c + 1) * BB + b) * REC + j];      // prefetch next

    float nt = 0.f;
    if (j < TT) {
#pragma unroll
      for (int s = 0; s < TT; ++s) nt = fmaf(al[s], lds[s * TT + j], nt);
    }
    float lc  = lds[49];
    float scc = lds[50];
    float mcc = lds[51];
    __syncthreads();

    float na[TT];
#pragma unroll
    for (int t = 0; t < TT; ++t) na[t] = __shfl(nt, t);
    float mx = na[0];
#pragma unroll
    for (int t = 1; t < TT; ++t) mx = fmaxf(mx, na[t]);
    float inv = 1.0f / mx;
#pragma unroll
    for (int t = 0; t < TT; ++t) al[t] = na[t] * inv;
    lacc += logf(mx) + lc;
    sc += scc; mcf += mcc;
  }

  if (j == 0) {
    float z = 0.f;
#pragma unroll
    for (int t = 0; t < TT; ++t) z += al[t] * expf(end_t[t]);
    float logZ = lacc + logf(z);
    int t0 = tags[b];
    float s0 = start_t[t0] + em[(size_t)b * TT + t0];
    int se = (int)mcf - 1;
    int te = tags[(size_t)se * BB + b];
    results[b] = (sc + s0 + end_t[te]) - logZ;
  }
}

// ---------------------------------------------------------------------------
// Kernel 3: deterministic tree-reduce of the 2048 per-batch results.
// ---------------------------------------------------------------------------
__global__ __launch_bounds__(256)
void crf_reduce_kernel(const float* __restrict__ results, float* __restrict__ out) {
  __shared__ float s[256];
  int t = threadIdx.x;
  float v = 0.f;
  for (int i = t; i < BB; i += 256) v += results[i];
  s[t] = v;
  __syncthreads();
  for (int off = 128; off > 0; off >>= 1) {
    if (t < off) s[t] += s[t + off];
    __syncthreads();
  }
  if (t == 0) out[0] = s[0];
}

extern "C" void kernel_launch(void* const* d_in, const int* in_sizes, int n_in,
                              void* d_out, int out_size, void* d_ws, size_t ws_size,
                              hipStream_t stream) {
  const float* em      = (const float*)d_in[0];
  const int*   tags    = (const int*)d_in[1];
  const int*   qmask   = (const int*)d_in[2];
  const int*   mask    = (const int*)d_in[3];
  const float* start_t = (const float*)d_in[4];
  const float* end_t   = (const float*)d_in[5];
  const float* self_t  = (const float*)d_in[6];
  const float* other_t = (const float*)d_in[7];

  float* recs = (float*)d_ws;

  // choose chunk count to fit workspace: K*B*REC*4 + B*4 bytes
  int K = 64;
  auto need = [](int k) { return (size_t)k * BB * REC * 4 + (size_t)BB * 4; };
  if      (ws_size >= need(64)) K = 64;
  else if (ws_size >= need(32)) K = 32;
  else if (ws_size >= need(16)) K = 16;
  else if (ws_size >= need(8))  K = 8;
  else                          K = 4;

  float* results = recs + (size_t)K * BB * REC;

  int threads = 256;
  int blocks = (K * BB) / 128;   // 128 chunks per block, 2 threads each
  switch (K) {
    case 64: crf_chunk_kernel<64><<<blocks, threads, 0, stream>>>(em, tags, qmask, mask, self_t, other_t, recs); break;
    case 32: crf_chunk_kernel<32><<<blocks, threads, 0, stream>>>(em, tags, qmask, mask, self_t, other_t, recs); break;
    case 16: crf_chunk_kernel<16><<<blocks, threads, 0, stream>>>(em, tags, qmask, mask, self_t, other_t, recs); break;
    case 8:  crf_chunk_kernel<8 ><<<blocks, threads, 0, stream>>>(em, tags, qmask, mask, self_t, other_t, recs); break;
    default: crf_chunk_kernel<4 ><<<blocks, threads, 0, stream>>>(em, tags, qmask, mask, self_t, other_t, recs); break;
  }

  crf_combine_kernel<<<BB, 64, 0, stream>>>(recs, em, tags, start_t, end_t, results, K);
  crf_reduce_kernel<<<1, 256, 0, stream>>>(results, (float*)d_out);
}

// Round 6
// 96.124 us; speedup vs baseline: 8.5179x; 8.5179x over previous
//
#include <hip/hip_runtime.h>
#include <hip/hip_bf16.h>

#define LSEQ 2048
#define BB   2048
#define TT   7
#define REC  52   // 49 matrix + scale + score + maskcnt (float), 208 B = 16B-aligned

typedef float v2f __attribute__((ext_vector_type(2)));

// ---------------------------------------------------------------------------
// Kernel 1: one thread per (batch, chunk). Composite operator in exp-space:
//   M <- (M x E) o colscale(exp(em_i)),  E = exp(transitions) per cont flag.
// float2-vectorized over a column-padded (7x8) E to enable v_pk_fma_f32.
// Software-pipelined: step i+1's loads issue before step i's fma block.
// ---------------------------------------------------------------------------
template<int K>
__global__ __launch_bounds__(256)
void crf_chunk_kernel(const float* __restrict__ em,
                      const int*   __restrict__ tags,
                      const int*   __restrict__ qmask,
                      const int*   __restrict__ mask,
                      const float* __restrict__ self_t,
                      const float* __restrict__ other_t,
                      float* __restrict__ recs) {
  constexpr int C = LSEQ / K;
  __shared__ __align__(16) float sE[2][64];   // exp(trans), row stride 8 (col 7 = 0)
  __shared__ float sT[2][49];                 // raw transitions (gold-path score)
  int tid = threadIdx.x;
  if (tid < 64) { sE[0][tid] = 0.f; sE[1][tid] = 0.f; }
  __syncthreads();
  if (tid < 49) {
    int r = tid / 7, t2 = tid - r * 7;
    float sv = self_t[tid];
    float ov = other_t[tid];
    sE[0][r * 8 + t2] = __expf(sv);
    sE[1][r * 8 + t2] = __expf(ov);
    sT[0][tid] = sv;
    sT[1][tid] = ov;
  }
  __syncthreads();

  int gid = blockIdx.x * 256 + tid;
  int b = gid & (BB - 1);
  int c = gid >> 11;            // gid / BB

  v2f Mv[7][4];                 // row-major, col 7 padded (always 0)
#pragma unroll
  for (int s = 0; s < 7; ++s)
#pragma unroll
    for (int j = 0; j < 4; ++j)
      Mv[s][j] = (v2f){ (s == 2 * j) ? 1.f : 0.f, (s == 2 * j + 1) ? 1.f : 0.f };

  float sc = 0.0f;
  int   mc = 0;
  int i0    = c * C;
  int i_end = i0 + C;
  int tp, qp;
  if (c == 0) {
    mc = mask[b];               // include i=0 in the mask count
    tp = tags[b];
    qp = qmask[b];
    i0 = 1;                     // step 0 is the alpha-init (combine kernel)
  } else {
    tp = tags[(size_t)(i0 - 1) * BB + b];
    qp = qmask[(size_t)(i0 - 1) * BB + b];
  }

  const float* em_p = em    + ((size_t)i0 * BB + b) * TT;
  const int*   qm_p = qmask + (size_t)i0 * BB + b;
  const int*   mk_p = mask  + (size_t)i0 * BB + b;
  const int*   tg_p = tags  + (size_t)i0 * BB + b;

  v2f Ev[7][4];
  int contPrev = -1;            // force initial load

  auto do_step = [&](float x0, float x1, float x2, float x3, float x4, float x5,
                     float x6, int tg, int qm, int mi) {
    int cont = (qm != qp) ? 1 : 0;
    if (__any(cont != contPrev)) {
#pragma unroll
      for (int r = 0; r < 7; ++r)
#pragma unroll
        for (int j = 0; j < 4; ++j)
          Ev[r][j] = *reinterpret_cast<const v2f*>(&sE[cont][r * 8 + 2 * j]);
      contPrev = cont;
    }

    v2f ee[4];
    ee[0] = (v2f){ __expf(x0), __expf(x1) };
    ee[1] = (v2f){ __expf(x2), __expf(x3) };
    ee[2] = (v2f){ __expf(x4), __expf(x5) };
    ee[3] = (v2f){ __expf(x6), 1.0f };

    // gold-path score: select em[tag] from already-loaded regs (no extra load)
    float etag = x0;
    etag = (tg == 1) ? x1 : etag;
    etag = (tg == 2) ? x2 : etag;
    etag = (tg == 3) ? x3 : etag;
    etag = (tg == 4) ? x4 : etag;
    etag = (tg == 5) ? x5 : etag;
    etag = (tg == 6) ? x6 : etag;
    float ttag = sT[cont][tp * 7 + tg];
    if (mi) { sc += ttag + etag; ++mc; }
    tp = tg; qp = qm;

    if (!__any(mi == 0)) {
#pragma unroll
      for (int s = 0; s < 7; ++s) {
        v2f a0 = (v2f){0.f,0.f}, a1 = (v2f){0.f,0.f},
            a2 = (v2f){0.f,0.f}, a3 = (v2f){0.f,0.f};
#pragma unroll
        for (int r = 0; r < 7; ++r) {
          float ms = (r & 1) ? Mv[s][r >> 1].y : Mv[s][r >> 1].x;
          v2f mb = (v2f){ ms, ms };
          a0 = mb * Ev[r][0] + a0;
          a1 = mb * Ev[r][1] + a1;
          a2 = mb * Ev[r][2] + a2;
          a3 = mb * Ev[r][3] + a3;
        }
        Mv[s][0] = a0 * ee[0];
        Mv[s][1] = a1 * ee[1];
        Mv[s][2] = a2 * ee[2];
        Mv[s][3] = a3 * ee[3];
      }
    } else {
#pragma unroll
      for (int s = 0; s < 7; ++s) {
        v2f a0 = (v2f){0.f,0.f}, a1 = (v2f){0.f,0.f},
            a2 = (v2f){0.f,0.f}, a3 = (v2f){0.f,0.f};
#pragma unroll
        for (int r = 0; r < 7; ++r) {
          float ms = (r & 1) ? Mv[s][r >> 1].y : Mv[s][r >> 1].x;
          v2f mb = (v2f){ ms, ms };
          a0 = mb * Ev[r][0] + a0;
          a1 = mb * Ev[r][1] + a1;
          a2 = mb * Ev[r][2] + a2;
          a3 = mb * Ev[r][3] + a3;
        }
        Mv[s][0] = mi ? a0 * ee[0] : Mv[s][0];
        Mv[s][1] = mi ? a1 * ee[1] : Mv[s][1];
        Mv[s][2] = mi ? a2 * ee[2] : Mv[s][2];
        Mv[s][3] = mi ? a3 * ee[3] : Mv[s][3];
      }
    }
  };

  // software pipeline: load step i+1 before computing step i
  float e0 = em_p[0], e1 = em_p[1], e2 = em_p[2], e3 = em_p[3],
        e4 = em_p[4], e5 = em_p[5], e6 = em_p[6];
  int tg = *tg_p, qm = *qm_p, mi = *mk_p;

  for (int i = i0; i < i_end - 1; ++i) {
    em_p += (size_t)BB * TT;
    qm_p += BB; mk_p += BB; tg_p += BB;
    float n0 = em_p[0], n1 = em_p[1], n2 = em_p[2], n3 = em_p[3],
          n4 = em_p[4], n5 = em_p[5], n6 = em_p[6];
    int ntg = *tg_p, nqm = *qm_p, nmi = *mk_p;

    do_step(e0, e1, e2, e3, e4, e5, e6, tg, qm, mi);

    e0 = n0; e1 = n1; e2 = n2; e3 = n3; e4 = n4; e5 = n5; e6 = n6;
    tg = ntg; qm = nqm; mi = nmi;
  }
  do_step(e0, e1, e2, e3, e4, e5, e6, tg, qm, mi);

  // renormalize and write record (all entries positive; pad col is 0)
  float mx = Mv[0][0].x;
#pragma unroll
  for (int s = 0; s < 7; ++s)
#pragma unroll
    for (int j = 0; j < 4; ++j) {
      mx = fmaxf(mx, Mv[s][j].x);
      mx = fmaxf(mx, Mv[s][j].y);
    }
  float inv = 1.0f / mx;

  float outv[REC];
#pragma unroll
  for (int s = 0; s < 7; ++s) {
    outv[s*7+0] = Mv[s][0].x * inv;
    outv[s*7+1] = Mv[s][0].y * inv;
    outv[s*7+2] = Mv[s][1].x * inv;
    outv[s*7+3] = Mv[s][1].y * inv;
    outv[s*7+4] = Mv[s][2].x * inv;
    outv[s*7+5] = Mv[s][2].y * inv;
    outv[s*7+6] = Mv[s][3].x * inv;
  }
  outv[49] = logf(mx);
  outv[50] = sc;
  outv[51] = (float)mc;

  float4* rp = reinterpret_cast<float4*>(recs + ((size_t)c * BB + b) * REC);
#pragma unroll
  for (int k2 = 0; k2 < 13; ++k2)
    rp[k2] = make_float4(outv[4*k2+0], outv[4*k2+1], outv[4*k2+2], outv[4*k2+3]);
}

// ---------------------------------------------------------------------------
// Kernel 2: one wave per batch; sequentially fold the K chunk operators into
// the alpha vector (exp-space, renormalized each step), then finish score/logZ.
// ---------------------------------------------------------------------------
__global__ __launch_bounds__(64)
void crf_combine_kernel(const float* __restrict__ recs,
                        const float* __restrict__ em,
                        const int*   __restrict__ tags,
                        const float* __restrict__ start_t,
                        const float* __restrict__ end_t,
                        float* __restrict__ results,
                        int K) {
  int b = blockIdx.x;
  int j = threadIdx.x;
  __shared__ float lds[REC];

  float al[TT];
#pragma unroll
  for (int t = 0; t < TT; ++t) al[t] = expf(start_t[t] + em[(size_t)b * TT + t]);

  float lacc = 0.f, sc = 0.f, mcf = 0.f;
  float r = (j < REC) ? recs[(size_t)b * REC + j] : 0.f;   // record (c=0, b)

  for (int c = 0; c < K; ++c) {
    if (j < REC) lds[j] = r;
    __syncthreads();
    if (c + 1 < K && j < REC)
      r = recs[((size_t)(c + 1) * BB + b) * REC + j];      // prefetch next

    float nt = 0.f;
    if (j < TT) {
#pragma unroll
      for (int s = 0; s < TT; ++s) nt = fmaf(al[s], lds[s * TT + j], nt);
    }
    float lc  = lds[49];
    float scc = lds[50];
    float mcc = lds[51];
    __syncthreads();

    float na[TT];
#pragma unroll
    for (int t = 0; t < TT; ++t) na[t] = __shfl(nt, t);
    float mx = na[0];
#pragma unroll
    for (int t = 1; t < TT; ++t) mx = fmaxf(mx, na[t]);
    float inv = 1.0f / mx;
#pragma unroll
    for (int t = 0; t < TT; ++t) al[t] = na[t] * inv;
    lacc += logf(mx) + lc;
    sc += scc; mcf += mcc;
  }

  if (j == 0) {
    float z = 0.f;
#pragma unroll
    for (int t = 0; t < TT; ++t) z += al[t] * expf(end_t[t]);
    float logZ = lacc + logf(z);
    int t0 = tags[b];
    float s0 = start_t[t0] + em[(size_t)b * TT + t0];
    int se = (int)mcf - 1;
    int te = tags[(size_t)se * BB + b];
    results[b] = (sc + s0 + end_t[te]) - logZ;
  }
}

// ---------------------------------------------------------------------------
// Kernel 3: deterministic tree-reduce of the 2048 per-batch results.
// ---------------------------------------------------------------------------
__global__ __launch_bounds__(256)
void crf_reduce_kernel(const float* __restrict__ results, float* __restrict__ out) {
  __shared__ float s[256];
  int t = threadIdx.x;
  float v = 0.f;
  for (int i = t; i < BB; i += 256) v += results[i];
  s[t] = v;
  __syncthreads();
  for (int off = 128; off > 0; off >>= 1) {
    if (t < off) s[t] += s[t + off];
    __syncthreads();
  }
  if (t == 0) out[0] = s[0];
}

extern "C" void kernel_launch(void* const* d_in, const int* in_sizes, int n_in,
                              void* d_out, int out_size, void* d_ws, size_t ws_size,
                              hipStream_t stream) {
  const float* em      = (const float*)d_in[0];
  const int*   tags    = (const int*)d_in[1];
  const int*   qmask   = (const int*)d_in[2];
  const int*   mask    = (const int*)d_in[3];
  const float* start_t = (const float*)d_in[4];
  const float* end_t   = (const float*)d_in[5];
  const float* self_t  = (const float*)d_in[6];
  const float* other_t = (const float*)d_in[7];

  float* recs = (float*)d_ws;

  // choose chunk count to fit workspace: K*B*REC*4 + B*4 bytes
  int K = 64;
  auto need = [](int k) { return (size_t)k * BB * REC * 4 + (size_t)BB * 4; };
  if      (ws_size >= need(64)) K = 64;
  else if (ws_size >= need(32)) K = 32;
  else if (ws_size >= need(16)) K = 16;
  else if (ws_size >= need(8))  K = 8;
  else                          K = 4;

  float* results = recs + (size_t)K * BB * REC;

  int threads = 256;
  int blocks = (K * BB) / threads;
  switch (K) {
    case 64: crf_chunk_kernel<64><<<blocks, threads, 0, stream>>>(em, tags, qmask, mask, self_t, other_t, recs); break;
    case 32: crf_chunk_kernel<32><<<blocks, threads, 0, stream>>>(em, tags, qmask, mask, self_t, other_t, recs); break;
    case 16: crf_chunk_kernel<16><<<blocks, threads, 0, stream>>>(em, tags, qmask, mask, self_t, other_t, recs); break;
    case 8:  crf_chunk_kernel<8 ><<<blocks, threads, 0, stream>>>(em, tags, qmask, mask, self_t, other_t, recs); break;
    default: crf_chunk_kernel<4 ><<<blocks, threads, 0, stream>>>(em, tags, qmask, mask, self_t, other_t, recs); break;
  }

  crf_combine_kernel<<<BB, 64, 0, stream>>>(recs, em, tags, start_t, end_t, results, K);
  crf_reduce_kernel<<<1, 256, 0, stream>>>(results, (float*)d_out);
}